// Round 4
// baseline (382.154 us; speedup 1.0000x reference)
//
#include <hip/hip_runtime.h>
#include <hip/hip_bf16.h>
#include <cstdint>
#include <cstddef>

// Problem constants (B,S,D,H fixed by the reference)
#define Bc 4
#define Sc 2048
#define Dc 1024
#define Hc 16
// HD = 64

typedef __bf16 bf16;
typedef bf16  bf16x4 __attribute__((ext_vector_type(4)));
typedef bf16  bf16x8 __attribute__((ext_vector_type(8)));
typedef float f32x4  __attribute__((ext_vector_type(4)));

__device__ __forceinline__ void load_lds16(const bf16* g, bf16* l) {
    __builtin_amdgcn_global_load_lds((const __attribute__((address_space(1))) void*)g,
                                     (__attribute__((address_space(3))) void*)l,
                                     16, 0, 0);
}

// 16 fp32 -> two bf16x8
__device__ __forceinline__ void cvt16(const float* __restrict__ g,
                                      bf16x8& lo, bf16x8& hi) {
    const f32x4 a0 = *(const f32x4*)(g);
    const f32x4 a1 = *(const f32x4*)(g + 4);
    const f32x4 a2 = *(const f32x4*)(g + 8);
    const f32x4 a3 = *(const f32x4*)(g + 12);
#pragma unroll
    for (int j = 0; j < 4; j++) {
        lo[j]     = (bf16)a0[j];
        lo[j + 4] = (bf16)a1[j];
        hi[j]     = (bf16)a2[j];
        hi[j + 4] = (bf16)a3[j];
    }
}

__device__ __forceinline__ void store_relu(float* p, float v) { *p = fmaxf(v, 0.0f); }
__device__ __forceinline__ void store_relu(bf16*  p, float v) { *p = (bf16)fmaxf(v, 0.0f); }

// ---------------------------------------------------------------------------
// fp32 -> bf16 conversion (16 elems/thread)
// ---------------------------------------------------------------------------
__global__ __launch_bounds__(256)
void cvt_f32_bf16(const float* __restrict__ src, bf16* __restrict__ dst, int n16) {
    const int idx = blockIdx.x * 256 + threadIdx.x;
    if (idx >= n16) return;
    bf16x8 lo, hi;
    cvt16(src + (size_t)idx * 16, lo, hi);
    *(bf16x8*)(dst + (size_t)idx * 16)     = lo;
    *(bf16x8*)(dst + (size_t)idx * 16 + 8) = hi;
}

// 4 weight matrices in one launch (dst blocks contiguous: Wqb|Wkb|Wvb|Wob).
__global__ __launch_bounds__(256)
void cvt_w4(const float* __restrict__ s0, const float* __restrict__ s1,
            const float* __restrict__ s2, const float* __restrict__ s3,
            bf16* __restrict__ dst) {
    const float* srcs[4] = {s0, s1, s2, s3};
    const float* src = srcs[blockIdx.y];
    const int idx = blockIdx.x * 256 + threadIdx.x;
    bf16x8 lo, hi;
    cvt16(src + (size_t)idx * 16, lo, hi);
    bf16* d = dst + (size_t)blockIdx.y * ((size_t)Dc * Dc) + (size_t)idx * 16;
    *(bf16x8*)d       = lo;
    *(bf16x8*)(d + 8) = hi;
}

// ---------------------------------------------------------------------------
// GEMM: C = relu(A[M,K] @ W[N,K]^T + bias), bf16 in, fp32 accum.
// 128x128 tile, BK=64 (16 k-iters), global_load_lds width-16 staging.
// LDS uses XOR swizzle: logical (row,col) stored at row*64 + (col ^ ((row&7)*8))
// -> all ds_read_b128 fragment reads are 2-way (free) instead of 8-16-way.
// TR=true: V-projection epilogue writes per-head transposed Vt_g[b][h][hd][s],
// reusing the main LDS pool for the transpose buffer.
// ---------------------------------------------------------------------------
#define BM 128
#define BN 128
#define BK 64

template <typename TC, bool TR>
__global__ __launch_bounds__(256)
void gemm_bb(const bf16* __restrict__ A, const bf16* __restrict__ W,
             const float* __restrict__ bias, TC* __restrict__ C,
             int M, int N, int K) {
    constexpr int POOL = TR ? 36864 : 32768;      // bytes
    __shared__ __align__(16) char pool[POOL];
    bf16* lA = (bf16*)pool;                        // [BM*BK] = 16 KB
    bf16* lB = (bf16*)(pool + 16384);              // [BN*BK] = 16 KB

    const int t    = threadIdx.x;
    const int lane = t & 63;
    const int wave = t >> 6;
    const int l15  = lane & 15;
    const int quad = lane >> 4;

    const int m0 = blockIdx.x * BM;
    const int n0 = blockIdx.y * BN;
    const int wm = (wave >> 1) * 64;
    const int wn = (wave & 1) * 64;

    f32x4 acc[4][4] = {};

    // staging map: thread t, chunk c: flat slot f = t*8 + c*2048
    //   row = f>>6 = (t>>3) + 32c ; stored col = (t&7)*8 ;
    //   logical col cg = stored ^ ((row&7)*8), row&7 == (t>>3)&7 for all c.
    const int srow = t >> 3;                          // 0..31
    const int cg   = (((t & 7) ^ (srow & 7)) << 3);   // swizzled logical col
    const bf16* gA = A + (size_t)(m0 + srow) * K + cg;
    const bf16* gW = W + (size_t)(n0 + srow) * K + cg;
    bf16* lA0 = lA + t * 8;
    bf16* lB0 = lB + t * 8;

    for (int k0 = 0; k0 < K; k0 += BK) {
        __syncthreads();               // previous tiles fully consumed
#pragma unroll
        for (int c = 0; c < 4; c++) {
            load_lds16(gA + (size_t)(32 * c) * K, lA0 + c * 2048);
            load_lds16(gW + (size_t)(32 * c) * K, lB0 + c * 2048);
        }
        gA += BK; gW += BK;
        __syncthreads();               // drains vmcnt -> tiles published

#pragma unroll
        for (int ks = 0; ks < 2; ks++) {
            bf16x8 af[4], bfr[4];
#pragma unroll
            for (int mt = 0; mt < 4; mt++) {
                const int row = wm + mt * 16 + l15;
                const int colp = ((((ks << 2) | quad) ^ (l15 & 7)) << 3);
                af[mt] = *(const bf16x8*)(lA + row * BK + colp);
            }
#pragma unroll
            for (int nt = 0; nt < 4; nt++) {
                const int row = wn + nt * 16 + l15;
                const int colp = ((((ks << 2) | quad) ^ (l15 & 7)) << 3);
                bfr[nt] = *(const bf16x8*)(lB + row * BK + colp);
            }
#pragma unroll
            for (int mt = 0; mt < 4; mt++)
#pragma unroll
                for (int nt = 0; nt < 4; nt++)
                    acc[mt][nt] = __builtin_amdgcn_mfma_f32_16x16x32_bf16(
                        af[mt], bfr[nt], acc[mt][nt], 0, 0, 0);
        }
    }

    if constexpr (!TR) {
        // C/D layout: col = lane&15, row = quad*4 + i
#pragma unroll
        for (int nt = 0; nt < 4; nt++) {
            const int col = n0 + wn + nt * 16 + l15;
            const float bv = bias[col];
#pragma unroll
            for (int mt = 0; mt < 4; mt++) {
                const int rowb = m0 + wm + mt * 16 + quad * 4;
#pragma unroll
                for (int i = 0; i < 4; i++)
                    store_relu(&C[(size_t)(rowb + i) * N + col], acc[mt][nt][i] + bv);
            }
        }
    } else {
        // Transposed per-head output. Reuse pool as tr[4][64][72] (36864 B).
        __syncthreads();               // everyone done reading lA/lB
        bf16* trp = (bf16*)pool;       // tr[w][r][c] = trp[(w*64+r)*72 + c]
#pragma unroll
        for (int nt = 0; nt < 4; nt++) {
            const int col = n0 + wn + nt * 16 + l15;
            const float bv = bias[col];
#pragma unroll
            for (int mt = 0; mt < 4; mt++)
#pragma unroll
                for (int i = 0; i < 4; i++)
                    trp[((wave * 64) + nt * 16 + l15) * 72 + mt * 16 + quad * 4 + i] =
                        (bf16)fmaxf(acc[mt][nt][i] + bv, 0.0f);
        }
        __syncthreads();
        const int r2 = lane >> 3;          // 0..7
        const int c8 = (lane & 7) * 8;     // 0..56
#pragma unroll
        for (int rr = 0; rr < 8; rr++) {
            const int rt = rr * 8 + r2;                  // quadrant col (hd dim)
            const bf16x8 vv = *(const bf16x8*)&trp[((wave * 64) + rt) * 72 + c8];
            const int cg2 = n0 + wn + rt;                // global col
            const int h   = cg2 >> 6, hd = cg2 & 63;
            const int mg  = m0 + wm + c8;                // global row base
            const int b   = mg >> 11, s = mg & (Sc - 1);
            bf16* dst = (bf16*)C + ((size_t)(b * Hc + h) * 64 + hd) * Sc + s;
            *(bf16x8*)dst = vv;
        }
    }
}

// ---------------------------------------------------------------------------
// Flash attention, transposed-score form, FIXED-MAX softmax.
// Q,K are post-ReLU => all scores >= 0 and bounded, so p = exp2(s) with no
// running max / rescale; normalization sum via ones-MFMA, applied at end.
//
// 256 queries/block, 64 queries/wave (QI=4). Grid = 8x64 = 512 blocks ->
// occupancy is GRID-capped at 2 blocks/CU (2 waves/SIMD).
// THIS ROUND: K/V LDS double-buffer -> ONE barrier per key-tile (was 2).
//  iter kt: write buf (kt&1) [data loaded last iter] -> issue next-tile
//  global loads -> barrier -> compute from buf.  Race-free: a wave writing
//  buf cur at iter kt passed B(kt-1); any wave at B(kt-1) already finished
//  its reads of cur at iter kt-2 (program order). Halves barrier drains and
//  lets waves slip a full compute phase relative to each other.
//  Pl is a 2-slot ping-pong [4][2][16][72] (process qi in pairs; the WAR on
//  a slot is same-wave and the DS pipe is in-order per wave). LDS = 55296 B.
//  + T14 issue-early, ones-MFMA denominator, raw v_exp_f32, s_setprio.
// V pre-transposed per head: Vt_g[b][h][hd][s]. O accumulated transposed.
// ---------------------------------------------------------------------------
#define QI 4

__global__ __launch_bounds__(256)
void attn_flash(const bf16* __restrict__ Qh, const bf16* __restrict__ Kh,
                const bf16* __restrict__ Vt_g, bf16* __restrict__ Y) {
    __shared__ __align__(16) bf16 Kl[2][64][72];       // [buf][key][hd]  18432 B
    __shared__ __align__(16) bf16 Vl[2][64][72];       // [buf][hd][key]  18432 B
    __shared__ __align__(16) bf16 Pl[4][2][16][72];    // per-wave 2-slot 18432 B

    const int t    = threadIdx.x;
    const int lane = t & 63;
    const int wave = t >> 6;
    const int l15  = lane & 15;
    const int quad = lane >> 4;

    const int qt = blockIdx.x;          // 0..7
    const int bh = blockIdx.y;          // 0..63
    const int b  = bh >> 4;
    const int h  = bh & 15;
    const int q0 = qt * 256;
    const size_t rowbase = (size_t)b * Sc;
    const size_t vhead   = (size_t)(b * Hc + h) * 64;

    // Q fragments as B-operand [n=query=l15][k=hd=quad*8+j], prescaled by
    // 1/8 * log2(e) so scores land in the exp2 domain.
    const float qscale = 0.125f * 1.44269504f;
    bf16x8 qf[QI][2];
#pragma unroll
    for (int qi = 0; qi < QI; qi++) {
        const bf16* qp = Qh + (rowbase + q0 + wave * 64 + qi * 16 + l15) * (size_t)Dc + h * 64;
#pragma unroll
        for (int ks = 0; ks < 2; ks++) {
            const bf16x8 raw = *(const bf16x8*)(qp + ks * 32 + quad * 8);
#pragma unroll
            for (int j = 0; j < 8; j++) qf[qi][ks][j] = (bf16)((float)raw[j] * qscale);
        }
    }

    // ones fragment for the denominator MFMA (A-operand, all 1.0)
    bf16x8 ones;
#pragma unroll
    for (int j = 0; j < 8; j++) ones[j] = (bf16)1.0f;

    f32x4 yacc[QI][4] = {};             // O^T: col=query=l15, row=hd
    f32x4 sacc[QI]    = {};             // denominator: all rows = sum_k p

    // staging map: thread covers row sr, cols [sc, sc+16)
    const int sr = t >> 2;
    const int sc = (t & 3) * 16;
    constexpr int NT = Sc / 64;         // 32 key tiles

    // prologue: load tile 0 into regs
    const bf16* kp = Kh + (rowbase + sr) * (size_t)Dc + h * 64 + sc;
    const bf16* vp = Vt_g + (vhead + sr) * (size_t)Sc + sc;
    bf16x8 k0 = *(const bf16x8*)kp;
    bf16x8 k1 = *(const bf16x8*)(kp + 8);
    bf16x8 v0 = *(const bf16x8*)vp;
    bf16x8 v1 = *(const bf16x8*)(vp + 8);

    for (int kt = 0; kt < NT; kt++) {
        const int cur = kt & 1;
        // publish this tile into buf cur (loaded into regs last iter)
        *(bf16x8*)&Kl[cur][sr][sc]     = k0;
        *(bf16x8*)&Kl[cur][sr][sc + 8] = k1;
        *(bf16x8*)&Vl[cur][sr][sc]     = v0;
        *(bf16x8*)&Vl[cur][sr][sc + 8] = v1;

        // T14 issue-early: fetch NEXT tile into regs; latency hides under
        // this tile's compute.
        if (kt + 1 < NT) {
            kp += (size_t)64 * Dc;      // next 64 keys (rows of Kh)
            vp += 64;                   // next 64 keys (cols of Vt)
            k0 = *(const bf16x8*)kp;
            k1 = *(const bf16x8*)(kp + 8);
            v0 = *(const bf16x8*)vp;
            v1 = *(const bf16x8*)(vp + 8);
        }

        __syncthreads();                // single barrier: buf cur published

        // ---- K + V fragments (A-operands), shared across all qi ----
        bf16x8 kf[4][2], vf[4][2];
#pragma unroll
        for (int mt = 0; mt < 4; mt++) {
            kf[mt][0] = *(const bf16x8*)&Kl[cur][mt * 16 + l15][quad * 8];
            kf[mt][1] = *(const bf16x8*)&Kl[cur][mt * 16 + l15][32 + quad * 8];
        }
#pragma unroll
        for (int nt = 0; nt < 4; nt++) {
            vf[nt][0] = *(const bf16x8*)&Vl[cur][nt * 16 + l15][quad * 8];
            vf[nt][1] = *(const bf16x8*)&Vl[cur][nt * 16 + l15][32 + quad * 8];
        }

        // ---- process qi in pairs: A{2qp,2qp+1} then B{2qp,2qp+1} ----
#pragma unroll
        for (int qp = 0; qp < 2; qp++) {
            // phase A: QK^T -> exp2 -> P slot
#pragma unroll
            for (int qq = 0; qq < 2; qq++) {
                const int qi = qp * 2 + qq;
                f32x4 s[4];
                __builtin_amdgcn_s_setprio(1);
#pragma unroll
                for (int mt = 0; mt < 4; mt++) {
                    s[mt] = (f32x4){0.f, 0.f, 0.f, 0.f};
                    s[mt] = __builtin_amdgcn_mfma_f32_16x16x32_bf16(
                        kf[mt][0], qf[qi][0], s[mt], 0, 0, 0);
                    s[mt] = __builtin_amdgcn_mfma_f32_16x16x32_bf16(
                        kf[mt][1], qf[qi][1], s[mt], 0, 0, 0);
                }
                __builtin_amdgcn_s_setprio(0);
#pragma unroll
                for (int mt = 0; mt < 4; mt++) {
                    bf16x4 pk;
#pragma unroll
                    for (int i = 0; i < 4; i++)
                        pk[i] = (bf16)__builtin_amdgcn_exp2f(s[mt][i]);
                    *(bf16x4*)&Pl[wave][qq][l15][mt * 16 + quad * 4] = pk;
                }
            }

            // phase B: pf reads, then denominator + PV MFMAs
            bf16x8 pf[2][2];
#pragma unroll
            for (int qq = 0; qq < 2; qq++) {
                pf[qq][0] = *(const bf16x8*)&Pl[wave][qq][l15][quad * 8];
                pf[qq][1] = *(const bf16x8*)&Pl[wave][qq][l15][32 + quad * 8];
            }
            __builtin_amdgcn_s_setprio(1);
#pragma unroll
            for (int qq = 0; qq < 2; qq++) {
                const int qi = qp * 2 + qq;
                sacc[qi] = __builtin_amdgcn_mfma_f32_16x16x32_bf16(ones, pf[qq][0], sacc[qi], 0, 0, 0);
                sacc[qi] = __builtin_amdgcn_mfma_f32_16x16x32_bf16(ones, pf[qq][1], sacc[qi], 0, 0, 0);
#pragma unroll
                for (int nt = 0; nt < 4; nt++) {
                    yacc[qi][nt] = __builtin_amdgcn_mfma_f32_16x16x32_bf16(
                        vf[nt][0], pf[qq][0], yacc[qi][nt], 0, 0, 0);
                    yacc[qi][nt] = __builtin_amdgcn_mfma_f32_16x16x32_bf16(
                        vf[nt][1], pf[qq][1], yacc[qi][nt], 0, 0, 0);
                }
            }
            __builtin_amdgcn_s_setprio(0);
        }
    }

    // ---- normalize (denominator replicated in every lane), store ----
#pragma unroll
    for (int qi = 0; qi < QI; qi++) {
        const float inv = 1.0f / sacc[qi][0];
        bf16* yp = Y + (rowbase + q0 + wave * 64 + qi * 16 + l15) * (size_t)Dc + h * 64;
#pragma unroll
        for (int nt = 0; nt < 4; nt++)
#pragma unroll
            for (int i = 0; i < 4; i++)
                yp[nt * 16 + quad * 4 + i] = (bf16)(yacc[qi][nt][i] * inv);
    }
}

// ---------------------------------------------------------------------------
extern "C" void kernel_launch(void* const* d_in, const int* in_sizes, int n_in,
                              void* d_out, int out_size, void* d_ws, size_t ws_size,
                              hipStream_t stream) {
    const float* q  = (const float*)d_in[0];
    const float* k  = (const float*)d_in[1];
    const float* v  = (const float*)d_in[2];
    const float* Wq = (const float*)d_in[3];
    const float* bq = (const float*)d_in[4];
    const float* Wk = (const float*)d_in[5];
    const float* bk = (const float*)d_in[6];
    const float* Wv = (const float*)d_in[7];
    const float* bv = (const float*)d_in[8];
    const float* Wo = (const float*)d_in[9];
    const float* bo = (const float*)d_in[10];
    float* out = (float*)d_out;

    const int M = Bc * Sc;   // 8192
    const int N = Dc;        // 1024
    const int K = Dc;        // 1024
    const size_t E  = (size_t)Bc * Sc * Dc;  // 8388608
    const size_t EW = (size_t)Dc * Dc;       // 1048576

    // d_out: Qh | Kh (bf16; dead before final GEMM writes fp32).
    // d_ws:  tmpA | VtG | Wqb|Wkb|Wvb|Wob  (41.9 MB; proven in r5).
    bf16* Qh   = (bf16*)d_out;
    bf16* Kh   = Qh + E;
    bf16* tmpA = (bf16*)d_ws;
    bf16* VtG  = tmpA + E;
    bf16* Wqb  = VtG + E;
    bf16* Wkb  = Wqb + EW;
    bf16* Wvb  = Wkb + EW;
    bf16* Wob  = Wvb + EW;

    const int n16  = (int)(E / 16);          // 524288
    const int n16w = (int)(EW / 16);         // 65536
    dim3 gc(n16 / 256);                      // 2048
    dim3 gw4(n16w / 256, 4);                 // 256 x 4 (all four weights)
    dim3 gg(M / BM, N / BN);                 // 64 x 8
    dim3 ga(Sc / 256, Bc * Hc);              // 8 x 64

    cvt_w4<<<gw4, 256, 0, stream>>>(Wq, Wk, Wv, Wo, Wqb);

    cvt_f32_bf16<<<gc, 256, 0, stream>>>(q, tmpA, n16);
    gemm_bb<bf16, false><<<gg, 256, 0, stream>>>(tmpA, Wqb, bq, Qh, M, N, K);

    cvt_f32_bf16<<<gc, 256, 0, stream>>>(k, tmpA, n16);
    gemm_bb<bf16, false><<<gg, 256, 0, stream>>>(tmpA, Wkb, bk, Kh, M, N, K);

    cvt_f32_bf16<<<gc, 256, 0, stream>>>(v, tmpA, n16);
    gemm_bb<bf16, true><<<gg, 256, 0, stream>>>(tmpA, Wvb, bv, VtG, M, N, K);

    attn_flash<<<ga, 256, 0, stream>>>(Qh, Kh, VtG, tmpA);

    gemm_bb<float, false><<<gg, 256, 0, stream>>>(tmpA, Wob, bo, out, M, N, K);
}

// Round 5
// 376.888 us; speedup vs baseline: 1.0140x; 1.0140x over previous
//
#include <hip/hip_runtime.h>
#include <hip/hip_bf16.h>
#include <cstdint>
#include <cstddef>

// Problem constants (B,S,D,H fixed by the reference)
#define Bc 4
#define Sc 2048
#define Dc 1024
#define Hc 16
// HD = 64

typedef __bf16 bf16;
typedef bf16  bf16x4 __attribute__((ext_vector_type(4)));
typedef bf16  bf16x8 __attribute__((ext_vector_type(8)));
typedef float f32x4  __attribute__((ext_vector_type(4)));

__device__ __forceinline__ void load_lds16(const bf16* g, bf16* l) {
    __builtin_amdgcn_global_load_lds((const __attribute__((address_space(1))) void*)g,
                                     (__attribute__((address_space(3))) void*)l,
                                     16, 0, 0);
}

// 16 fp32 -> two bf16x8
__device__ __forceinline__ void cvt16(const float* __restrict__ g,
                                      bf16x8& lo, bf16x8& hi) {
    const f32x4 a0 = *(const f32x4*)(g);
    const f32x4 a1 = *(const f32x4*)(g + 4);
    const f32x4 a2 = *(const f32x4*)(g + 8);
    const f32x4 a3 = *(const f32x4*)(g + 12);
#pragma unroll
    for (int j = 0; j < 4; j++) {
        lo[j]     = (bf16)a0[j];
        lo[j + 4] = (bf16)a1[j];
        hi[j]     = (bf16)a2[j];
        hi[j + 4] = (bf16)a3[j];
    }
}

__device__ __forceinline__ void store_relu(float* p, float v) { *p = fmaxf(v, 0.0f); }
__device__ __forceinline__ void store_relu(bf16*  p, float v) { *p = (bf16)fmaxf(v, 0.0f); }

// ---------------------------------------------------------------------------
// fp32 -> bf16 conversion (16 elems/thread)
// ---------------------------------------------------------------------------
__global__ __launch_bounds__(256)
void cvt_f32_bf16(const float* __restrict__ src, bf16* __restrict__ dst, int n16) {
    const int idx = blockIdx.x * 256 + threadIdx.x;
    if (idx >= n16) return;
    bf16x8 lo, hi;
    cvt16(src + (size_t)idx * 16, lo, hi);
    *(bf16x8*)(dst + (size_t)idx * 16)     = lo;
    *(bf16x8*)(dst + (size_t)idx * 16 + 8) = hi;
}

// 4 weight matrices in one launch (dst blocks contiguous: Wqb|Wkb|Wvb|Wob).
__global__ __launch_bounds__(256)
void cvt_w4(const float* __restrict__ s0, const float* __restrict__ s1,
            const float* __restrict__ s2, const float* __restrict__ s3,
            bf16* __restrict__ dst) {
    const float* srcs[4] = {s0, s1, s2, s3};
    const float* src = srcs[blockIdx.y];
    const int idx = blockIdx.x * 256 + threadIdx.x;
    bf16x8 lo, hi;
    cvt16(src + (size_t)idx * 16, lo, hi);
    bf16* d = dst + (size_t)blockIdx.y * ((size_t)Dc * Dc) + (size_t)idx * 16;
    *(bf16x8*)d       = lo;
    *(bf16x8*)(d + 8) = hi;
}

// ---------------------------------------------------------------------------
// GEMM: C = relu(A[M,K] @ W[N,K]^T + bias), bf16 in, fp32 accum.
// THIS ROUND: BN 128->64. With N=1024 the old grid was 64x8=512 blocks =
// 2 blocks/CU (grid-capped occupancy, the m97-structure needs ~4/CU of
// independent blocks to hide its barrier drain). Now grid = 64x16 = 1024
// blocks = 4/CU; LDS 24.6 KB; acc halves to 4x2 frags (VGPR ~90).
// 128x64 tile, BK=64 (16 k-iters), global_load_lds width-16 staging.
// LDS XOR swizzle: logical (row,col) stored at row*64 + (col ^ ((row&7)*8)).
// TR=true: V-projection epilogue writes per-head transposed Vt_g[b][h][hd][s],
// per-wave 32x64 transpose buffer reusing the main LDS pool.
// ---------------------------------------------------------------------------
#define BM 128
#define BN 64
#define BK 64

template <typename TC, bool TR>
__global__ __launch_bounds__(256)
void gemm_bb(const bf16* __restrict__ A, const bf16* __restrict__ W,
             const float* __restrict__ bias, TC* __restrict__ C,
             int M, int N, int K) {
    __shared__ __align__(16) char pool[24576];
    bf16* lA = (bf16*)pool;                        // [BM*BK] = 16 KB
    bf16* lB = (bf16*)(pool + 16384);              // [BN*BK] =  8 KB

    const int t    = threadIdx.x;
    const int lane = t & 63;
    const int wave = t >> 6;
    const int l15  = lane & 15;
    const int quad = lane >> 4;

    const int m0 = blockIdx.x * BM;
    const int n0 = blockIdx.y * BN;
    const int wm = (wave >> 1) * 64;   // 0 / 64
    const int wn = (wave & 1) * 32;    // 0 / 32

    f32x4 acc[4][2] = {};

    // staging map: thread t, chunk c: flat slot f = t*8 + c*2048
    //   row = (t>>3) + 32c ; stored col = (t&7)*8 ;
    //   logical col cg = stored ^ ((row&7)*8), row&7 == (t>>3)&7 for all c.
    const int srow = t >> 3;                          // 0..31
    const int cg   = (((t & 7) ^ (srow & 7)) << 3);   // swizzled logical col
    const bf16* gA = A + (size_t)(m0 + srow) * K + cg;
    const bf16* gW = W + (size_t)(n0 + srow) * K + cg;
    bf16* lA0 = lA + t * 8;
    bf16* lB0 = lB + t * 8;

    for (int k0 = 0; k0 < K; k0 += BK) {
        __syncthreads();               // previous tiles fully consumed
#pragma unroll
        for (int c = 0; c < 4; c++)
            load_lds16(gA + (size_t)(32 * c) * K, lA0 + c * 2048);
#pragma unroll
        for (int c = 0; c < 2; c++)
            load_lds16(gW + (size_t)(32 * c) * K, lB0 + c * 2048);
        gA += BK; gW += BK;
        __syncthreads();               // drains vmcnt -> tiles published

#pragma unroll
        for (int ks = 0; ks < 2; ks++) {
            bf16x8 af[4], bfr[2];
            const int colp = ((((ks << 2) | quad) ^ (l15 & 7)) << 3);
#pragma unroll
            for (int mt = 0; mt < 4; mt++) {
                const int row = wm + mt * 16 + l15;
                af[mt] = *(const bf16x8*)(lA + row * BK + colp);
            }
#pragma unroll
            for (int nt = 0; nt < 2; nt++) {
                const int row = wn + nt * 16 + l15;
                bfr[nt] = *(const bf16x8*)(lB + row * BK + colp);
            }
#pragma unroll
            for (int mt = 0; mt < 4; mt++)
#pragma unroll
                for (int nt = 0; nt < 2; nt++)
                    acc[mt][nt] = __builtin_amdgcn_mfma_f32_16x16x32_bf16(
                        af[mt], bfr[nt], acc[mt][nt], 0, 0, 0);
        }
    }

    if constexpr (!TR) {
        // C/D layout: col = lane&15, row = quad*4 + i
#pragma unroll
        for (int nt = 0; nt < 2; nt++) {
            const int col = n0 + wn + nt * 16 + l15;
            const float bv = bias[col];
#pragma unroll
            for (int mt = 0; mt < 4; mt++) {
                const int rowb = m0 + wm + mt * 16 + quad * 4;
#pragma unroll
                for (int i = 0; i < 4; i++)
                    store_relu(&C[(size_t)(rowb + i) * N + col], acc[mt][nt][i] + bv);
            }
        }
    } else {
        // Transposed per-head output. Reuse pool as tr[4][32][72] (18432 B).
        __syncthreads();               // everyone done reading lA/lB
        bf16* trp = (bf16*)pool;       // tr[w][r][c] = trp[(w*32+r)*72 + c]
#pragma unroll
        for (int nt = 0; nt < 2; nt++) {
            const int col = n0 + wn + nt * 16 + l15;
            const float bv = bias[col];
#pragma unroll
            for (int mt = 0; mt < 4; mt++)
#pragma unroll
                for (int i = 0; i < 4; i++)
                    trp[((wave * 32) + nt * 16 + l15) * 72 + mt * 16 + quad * 4 + i] =
                        (bf16)fmaxf(acc[mt][nt][i] + bv, 0.0f);
        }
        __syncthreads();
        const int r2 = lane >> 3;          // 0..7
        const int c8 = (lane & 7) * 8;     // 0..56
#pragma unroll
        for (int rr = 0; rr < 4; rr++) {
            const int rt = rr * 8 + r2;                  // 0..31 (hd-dim col)
            const bf16x8 vv = *(const bf16x8*)&trp[((wave * 32) + rt) * 72 + c8];
            const int cg2 = n0 + wn + rt;                // global col
            const int h   = cg2 >> 6, hd = cg2 & 63;
            const int mg  = m0 + wm + c8;                // global row base
            const int b   = mg >> 11, s = mg & (Sc - 1);
            bf16* dst = (bf16*)C + ((size_t)(b * Hc + h) * 64 + hd) * Sc + s;
            *(bf16x8*)dst = vv;
        }
    }
}

// ---------------------------------------------------------------------------
// Flash attention, transposed-score form, FIXED-MAX softmax.
// Round-3 structure (best measured: 126.7 us): single-buffered K/V with
// 2 barriers/tile, batched phase A (all qi QK+exp2+P-store) then phase B
// (all pf reads + denominator/PV MFMAs), T14 issue-early global loads,
// ones-MFMA denominator, raw v_exp_f32, s_setprio around MFMA clusters.
// THIS ROUND: grid dims swapped (bh on x): all 8 q-tile blocks of one bh
// land on the same XCD (linear%8 = bh%8) -> K/V panel fetched once per XCD
// instead of 8x across XCDs. Expect FETCH_SIZE 139 -> ~80 MB.
// V pre-transposed per head: Vt_g[b][h][hd][s]. O accumulated transposed.
// ---------------------------------------------------------------------------
#define QI 4

__global__ __launch_bounds__(256)
void attn_flash(const bf16* __restrict__ Qh, const bf16* __restrict__ Kh,
                const bf16* __restrict__ Vt_g, bf16* __restrict__ Y) {
    __shared__ __align__(16) bf16 Kl[64][72];       // [key][hd]       9216 B
    __shared__ __align__(16) bf16 Vl[64][72];       // [hd][key]       9216 B
    __shared__ __align__(16) bf16 Pl[4][64][72];    // per-wave P^T   36864 B

    const int t    = threadIdx.x;
    const int lane = t & 63;
    const int wave = t >> 6;
    const int l15  = lane & 15;
    const int quad = lane >> 4;

    const int bh = blockIdx.x;          // 0..63  (x so same-bh blocks share XCD)
    const int qt = blockIdx.y;          // 0..7
    const int b  = bh >> 4;
    const int h  = bh & 15;
    const int q0 = qt * 256;
    const size_t rowbase = (size_t)b * Sc;
    const size_t vhead   = (size_t)(b * Hc + h) * 64;

    // Q fragments as B-operand [n=query=l15][k=hd=quad*8+j], prescaled by
    // 1/8 * log2(e) so scores land in the exp2 domain.
    const float qscale = 0.125f * 1.44269504f;
    bf16x8 qf[QI][2];
#pragma unroll
    for (int qi = 0; qi < QI; qi++) {
        const bf16* qp = Qh + (rowbase + q0 + wave * 64 + qi * 16 + l15) * (size_t)Dc + h * 64;
#pragma unroll
        for (int ks = 0; ks < 2; ks++) {
            const bf16x8 raw = *(const bf16x8*)(qp + ks * 32 + quad * 8);
#pragma unroll
            for (int j = 0; j < 8; j++) qf[qi][ks][j] = (bf16)((float)raw[j] * qscale);
        }
    }

    // ones fragment for the denominator MFMA (A-operand, all 1.0)
    bf16x8 ones;
#pragma unroll
    for (int j = 0; j < 8; j++) ones[j] = (bf16)1.0f;

    f32x4 yacc[QI][4] = {};             // O^T: col=query=l15, row=hd
    f32x4 sacc[QI]    = {};             // denominator: all rows = sum_k p

    // staging map: thread covers row sr, cols [sc, sc+16)
    const int sr = t >> 2;
    const int sc = (t & 3) * 16;
    constexpr int NT = Sc / 64;         // 32 key tiles

    // prologue: load tile 0 into regs
    const bf16* kp = Kh + (rowbase + sr) * (size_t)Dc + h * 64 + sc;
    const bf16* vp = Vt_g + (vhead + sr) * (size_t)Sc + sc;
    bf16x8 k0 = *(const bf16x8*)kp;
    bf16x8 k1 = *(const bf16x8*)(kp + 8);
    bf16x8 v0 = *(const bf16x8*)vp;
    bf16x8 v1 = *(const bf16x8*)(vp + 8);

    for (int kt = 0; kt < NT; kt++) {
        __syncthreads();                // prev tile fully consumed by all waves
        *(bf16x8*)&Kl[sr][sc]     = k0;
        *(bf16x8*)&Kl[sr][sc + 8] = k1;
        *(bf16x8*)&Vl[sr][sc]     = v0;
        *(bf16x8*)&Vl[sr][sc + 8] = v1;
        __syncthreads();                // tile published

        // T14 issue-early: fetch NEXT tile into regs; latency hides under
        // this tile's compute. (Uniform branch; regs double-buffer the LDS.)
        if (kt + 1 < NT) {
            kp += (size_t)64 * Dc;      // next 64 keys (rows of Kh)
            vp += 64;                   // next 64 keys (cols of Vt)
            k0 = *(const bf16x8*)kp;
            k1 = *(const bf16x8*)(kp + 8);
            v0 = *(const bf16x8*)vp;
            v1 = *(const bf16x8*)(vp + 8);
        }

        // ---- K fragments (A-operand [m=key][k=hd]), shared across all qi ----
        bf16x8 kf[4][2];
#pragma unroll
        for (int mt = 0; mt < 4; mt++) {
            kf[mt][0] = *(const bf16x8*)&Kl[mt * 16 + l15][quad * 8];
            kf[mt][1] = *(const bf16x8*)&Kl[mt * 16 + l15][32 + quad * 8];
        }

        // ---- phase A: per qi QK^T -> exp2 -> P store (round-trips batched) ----
#pragma unroll
        for (int qi = 0; qi < QI; qi++) {
            f32x4 s[4];
            __builtin_amdgcn_s_setprio(1);
#pragma unroll
            for (int mt = 0; mt < 4; mt++) {
                s[mt] = (f32x4){0.f, 0.f, 0.f, 0.f};
                s[mt] = __builtin_amdgcn_mfma_f32_16x16x32_bf16(
                    kf[mt][0], qf[qi][0], s[mt], 0, 0, 0);
                s[mt] = __builtin_amdgcn_mfma_f32_16x16x32_bf16(
                    kf[mt][1], qf[qi][1], s[mt], 0, 0, 0);
            }
            __builtin_amdgcn_s_setprio(0);
#pragma unroll
            for (int mt = 0; mt < 4; mt++) {
                bf16x4 pk;
#pragma unroll
                for (int i = 0; i < 4; i++)
                    pk[i] = (bf16)__builtin_amdgcn_exp2f(s[mt][i]);
                *(bf16x4*)&Pl[wave][qi * 16 + l15][mt * 16 + quad * 4] = pk;
            }
        }

        // ---- V fragments (A-operand [m=hd][k=key]) ----
        bf16x8 vf[4][2];
#pragma unroll
        for (int nt = 0; nt < 4; nt++) {
            vf[nt][0] = *(const bf16x8*)&Vl[nt * 16 + l15][quad * 8];
            vf[nt][1] = *(const bf16x8*)&Vl[nt * 16 + l15][32 + quad * 8];
        }

        // ---- phase B: all pf reads, then all denominator + PV MFMAs ----
        bf16x8 pf[QI][2];
#pragma unroll
        for (int qi = 0; qi < QI; qi++) {
            pf[qi][0] = *(const bf16x8*)&Pl[wave][qi * 16 + l15][quad * 8];
            pf[qi][1] = *(const bf16x8*)&Pl[wave][qi * 16 + l15][32 + quad * 8];
        }
        __builtin_amdgcn_s_setprio(1);
#pragma unroll
        for (int qi = 0; qi < QI; qi++) {
            sacc[qi] = __builtin_amdgcn_mfma_f32_16x16x32_bf16(ones, pf[qi][0], sacc[qi], 0, 0, 0);
            sacc[qi] = __builtin_amdgcn_mfma_f32_16x16x32_bf16(ones, pf[qi][1], sacc[qi], 0, 0, 0);
#pragma unroll
            for (int nt = 0; nt < 4; nt++) {
                yacc[qi][nt] = __builtin_amdgcn_mfma_f32_16x16x32_bf16(
                    vf[nt][0], pf[qi][0], yacc[qi][nt], 0, 0, 0);
                yacc[qi][nt] = __builtin_amdgcn_mfma_f32_16x16x32_bf16(
                    vf[nt][1], pf[qi][1], yacc[qi][nt], 0, 0, 0);
            }
        }
        __builtin_amdgcn_s_setprio(0);
    }

    // ---- normalize (denominator replicated in every lane), store ----
#pragma unroll
    for (int qi = 0; qi < QI; qi++) {
        const float inv = 1.0f / sacc[qi][0];
        bf16* yp = Y + (rowbase + q0 + wave * 64 + qi * 16 + l15) * (size_t)Dc + h * 64;
#pragma unroll
        for (int nt = 0; nt < 4; nt++)
#pragma unroll
            for (int i = 0; i < 4; i++)
                yp[nt * 16 + quad * 4 + i] = (bf16)(yacc[qi][nt][i] * inv);
    }
}

// ---------------------------------------------------------------------------
extern "C" void kernel_launch(void* const* d_in, const int* in_sizes, int n_in,
                              void* d_out, int out_size, void* d_ws, size_t ws_size,
                              hipStream_t stream) {
    const float* q  = (const float*)d_in[0];
    const float* k  = (const float*)d_in[1];
    const float* v  = (const float*)d_in[2];
    const float* Wq = (const float*)d_in[3];
    const float* bq = (const float*)d_in[4];
    const float* Wk = (const float*)d_in[5];
    const float* bk = (const float*)d_in[6];
    const float* Wv = (const float*)d_in[7];
    const float* bv = (const float*)d_in[8];
    const float* Wo = (const float*)d_in[9];
    const float* bo = (const float*)d_in[10];
    float* out = (float*)d_out;

    const int M = Bc * Sc;   // 8192
    const int N = Dc;        // 1024
    const int K = Dc;        // 1024
    const size_t E  = (size_t)Bc * Sc * Dc;  // 8388608
    const size_t EW = (size_t)Dc * Dc;       // 1048576

    // d_out: Qh | Kh (bf16; dead before final GEMM writes fp32).
    // d_ws:  tmpA | VtG | Wqb|Wkb|Wvb|Wob  (41.9 MB; proven in r5).
    bf16* Qh   = (bf16*)d_out;
    bf16* Kh   = Qh + E;
    bf16* tmpA = (bf16*)d_ws;
    bf16* VtG  = tmpA + E;
    bf16* Wqb  = VtG + E;
    bf16* Wkb  = Wqb + EW;
    bf16* Wvb  = Wkb + EW;
    bf16* Wob  = Wvb + EW;

    const int n16  = (int)(E / 16);          // 524288
    const int n16w = (int)(EW / 16);         // 65536
    dim3 gc(n16 / 256);                      // 2048
    dim3 gw4(n16w / 256, 4);                 // 256 x 4 (all four weights)
    dim3 gg(M / BM, N / BN);                 // 64 x 16 = 1024 blocks (4/CU)
    dim3 ga(Bc * Hc, Sc / 256);              // 64 x 8 (bh on x: XCD locality)

    cvt_w4<<<gw4, 256, 0, stream>>>(Wq, Wk, Wv, Wo, Wqb);

    cvt_f32_bf16<<<gc, 256, 0, stream>>>(q, tmpA, n16);
    gemm_bb<bf16, false><<<gg, 256, 0, stream>>>(tmpA, Wqb, bq, Qh, M, N, K);

    cvt_f32_bf16<<<gc, 256, 0, stream>>>(k, tmpA, n16);
    gemm_bb<bf16, false><<<gg, 256, 0, stream>>>(tmpA, Wkb, bk, Kh, M, N, K);

    cvt_f32_bf16<<<gc, 256, 0, stream>>>(v, tmpA, n16);
    gemm_bb<bf16, true><<<gg, 256, 0, stream>>>(tmpA, Wvb, bv, VtG, M, N, K);

    attn_flash<<<ga, 256, 0, stream>>>(Qh, Kh, VtG, tmpA);

    gemm_bb<float, false><<<gg, 256, 0, stream>>>(tmpA, Wob, bo, out, M, N, K);
}